// Round 6
// baseline (120.020 us; speedup 1.0000x reference)
//
#include <hip/hip_runtime.h>
#include <math.h>

#define WAVES_PER_BLOCK 4
#define BLOCK 256

typedef float f32x4 __attribute__((ext_vector_type(4)));

__global__ __launch_bounds__(BLOCK) void raster_kernel(
    const float* __restrict__ sigma,    // [N,3]
    const float* __restrict__ time_,    // [N]
    const float* __restrict__ charge,   // [N]
    const float* __restrict__ tail,     // [N,3]
    const float* __restrict__ gsp,      // [3]
    float* __restrict__ out_r,          // [N,10,10,10]
    float* __restrict__ out_off,        // [N,3] written as float values
    int n, int ndepo_per_wave)
{
    // per-wave scratch (no cross-wave sharing -> NO barriers anywhere)
    __shared__ float s_qw01[WAVES_PER_BLOCK][104];   // charge*w0[i0]*w1[i1]
    __shared__ float s_w2 [WAVES_PER_BLOCK][12];

    const int wave = threadIdx.x >> 6;
    const int lane = threadIdx.x & 63;
    const int wid  = blockIdx.x * WAVES_PER_BLOCK + wave;

    // BLOCKED assignment: this wave owns depos [d0, d0+ndepo_per_wave),
    // a contiguous 4000B*ndepo output range -> sequential DRAM sweep per wave
    // (mimics the fill kernel's row-friendly pattern).
    int d = wid * ndepo_per_wave;
    const int dend = min(d + ndepo_per_wave, n);

    const float g0 = gsp[0], g1 = gsp[1], g2 = gsp[2];

    // lane roles (loop-invariant): lanes 0..10 dim0 edges, 11..21 dim1, 22..32 dim2
    const int dim = lane / 11;            // 0..2 for lane<33
    const int k   = lane - dim * 11;      // 0..10
    const float gdim = (dim == 0) ? g0 : (dim == 1) ? g1 : g2;

    // A2 gather shuffle sources (loop-invariant):
    // w0[j] lives in lane j, w1[j] in lane 11+j, w2[j] in lane 22+j
    const int i0a = lane;                 // qw01 index, first half
    const int s0a = i0a / 10, s1a = 11 + i0a % 10;
    const int i0b = lane + 64;            // second half (valid if <100)
    const int s0b = i0b / 10, s1b = 11 + i0b % 10;

    float pt = 0.f, sg = 1.f, q = 0.f;
    // prefetch inputs for first depo
    if (d < dend) {
        if (lane < 33) {
            pt = (dim == 0) ? tail[(size_t)d*3 + 1]
               : (dim == 1) ? tail[(size_t)d*3 + 2]
               : time_[d];
            sg = sigma[(size_t)d*3 + dim];
        }
        q = charge[d];
    }

    for (; d < dend; ++d) {
        const int dn = d + 1;

        // ---- phase A: 33 edge CDFs in lanes 0..32 ----
        float cdf = 0.0f, iminf = 0.0f;
        if (lane < 33) {
            iminf = floorf((pt - 3.0f * sg) / gdim);
            float edge = (iminf + (float)k) * gdim;
            float z = (edge - pt) / (sg * 1.4142135623730951f);
            cdf = 0.5f * (1.0f + erff(z));
        }
        float cdf1 = __shfl_down(cdf, 1);
        float wv = cdf1 - cdf;            // per-cell weight, valid where k<10

        if (lane < 33 && k == 0)
            out_off[(size_t)d*3 + dim] = iminf;

        // ---- prefetch next depo's inputs (sequential -> L1 hits) ----
        float npt = 0.f, nsg = 1.f, nq = 0.f;
        if (dn < dend) {
            if (lane < 33) {
                npt = (dim == 0) ? tail[(size_t)dn*3 + 1]
                    : (dim == 1) ? tail[(size_t)dn*3 + 2]
                    : time_[dn];
                nsg = sigma[(size_t)dn*3 + dim];
            }
            nq = charge[dn];
        }

        // ---- phase A2: qw01 table via shuffle gather (wave-local) ----
        {
            float w0a = __shfl(wv, s0a);
            float w1a = __shfl(wv, s1a);
            s_qw01[wave][i0a] = q * w0a * w1a;
            float w0b = __shfl(wv, s0b);
            float w1b = __shfl(wv, s1b);
            if (i0b < 100) s_qw01[wave][i0b] = q * w0b * w1b;
            if (lane >= 22 && lane < 32) s_w2[wave][lane - 22] = wv;
        }
        // same-wave DS ops are in-order; no __syncthreads needed (per-wave data)

        // ---- phase B: 250 float4 coalesced stores (contiguous 4000B) ----
        {
            float* base = out_r + (size_t)d * 1000;
            const float* qw = s_qw01[wave];
            const float* w2 = s_w2[wave];
            #pragma unroll
            for (int cc = 0; cc < 4; ++cc) {
                int c = lane + cc * 64;
                if (c < 250) {
                    int f = 4 * c;
                    f32x4 v;
                    v.x = qw[(f    ) / 10] * w2[(f    ) % 10];
                    v.y = qw[(f + 1) / 10] * w2[(f + 1) % 10];
                    v.z = qw[(f + 2) / 10] * w2[(f + 2) % 10];
                    v.w = qw[(f + 3) / 10] * w2[(f + 3) % 10];
                    *reinterpret_cast<f32x4*>(base + f) = v;
                }
            }
        }

        pt = npt; sg = nsg; q = nq;
    }
}

extern "C" void kernel_launch(void* const* d_in, const int* in_sizes, int n_in,
                              void* d_out, int out_size, void* d_ws, size_t ws_size,
                              hipStream_t stream) {
    const float* sigma  = (const float*)d_in[0];
    const float* time_  = (const float*)d_in[1];
    const float* charge = (const float*)d_in[2];
    const float* tail   = (const float*)d_in[3];
    const float* gsp    = (const float*)d_in[4];

    const int n = in_sizes[1];          // N depos (time is [N])
    float* out_r   = (float*)d_out;
    float* out_off = out_r + (size_t)n * 1000;

    // 512 blocks x 4 waves = 2048 waves; each sweeps 64 consecutive depos
    // (256 KB contiguous store range) -> DRAM-row-friendly sequential streams,
    // ~8 streams per HBM pseudochannel.
    const int blocks = 512;
    const int nwaves = blocks * WAVES_PER_BLOCK;
    const int ndepo  = (n + nwaves - 1) / nwaves;   // 64 at N=131072

    raster_kernel<<<blocks, BLOCK, 0, stream>>>(sigma, time_, charge, tail, gsp,
                                                out_r, out_off, n, ndepo);
}

// Round 7
// 113.700 us; speedup vs baseline: 1.0556x; 1.0556x over previous
//
#include <hip/hip_runtime.h>
#include <math.h>

#define WAVES_PER_BLOCK 4
#define BLOCK 256

typedef float f32x4 __attribute__((ext_vector_type(4)));
typedef float f32x2 __attribute__((ext_vector_type(2)));

__global__ __launch_bounds__(BLOCK) void raster_kernel(
    const float* __restrict__ sigma,    // [N,3]
    const float* __restrict__ time_,    // [N]
    const float* __restrict__ charge,   // [N]
    const float* __restrict__ tail,     // [N,3]
    const float* __restrict__ gsp,      // [3]
    float* __restrict__ out_r,          // [N,10,10,10]
    float* __restrict__ out_off,        // [N,3] written as float values
    int n, int niter)
{
    // per-wave scratch (no cross-wave sharing -> NO barriers anywhere)
    __shared__ float s_qw01[WAVES_PER_BLOCK][104];  // charge*w0[i0]*w1[i1] (+pad)
    __shared__ float s_w2e [WAVES_PER_BLOCK][16];   // w2 wrap table: w2e[j]=w2[j%10], j<13

    const int wave = threadIdx.x >> 6;
    const int lane = threadIdx.x & 63;
    const int nwaves = gridDim.x * WAVES_PER_BLOCK;
    int d = blockIdx.x * WAVES_PER_BLOCK + wave;

    const float g0 = gsp[0], g1 = gsp[1], g2 = gsp[2];

    // lane roles (loop-invariant): lanes 0..10 dim0 edges, 11..21 dim1, 22..32 dim2
    const int dim = lane / 11;            // 0..2 for lane<33
    const int k   = lane - dim * 11;      // 0..10
    const float gdim = (dim == 0) ? g0 : (dim == 1) ? g1 : g2;

    // A2 gather shuffle sources (loop-invariant):
    // w0[j] lives in lane j, w1[j] in lane 11+j, w2[j] in lane 22+j
    const int i0a = lane;                 // qw01 index, first half
    const int s0a = i0a / 10, s1a = 11 + i0a % 10;
    const int i0b = lane + 64;            // second half (valid if <100)
    const int s0b = i0b / 10, s1b = 11 + i0b % 10;

    // phase-B loop-invariant per-chunk indices: c = lane+64cc, f = 4c
    // i2 = f%10 is ALWAYS EVEN -> w2e reads are 8B-aligned f32x2 pairs;
    // decade crossing within a chunk only when i2 == 8 (elements z,w).
    int  jc[4], i2c[4];
    bool on[4], cross[4];
    #pragma unroll
    for (int cc = 0; cc < 4; ++cc) {
        int c = lane + 64 * cc;
        on[cc]    = (c < 250);
        int f     = 4 * c;
        jc[cc]    = f / 10;
        i2c[cc]   = f % 10;
        cross[cc] = (i2c[cc] == 8);
    }

    const float* qw  = s_qw01[wave];
    const float* w2e = s_w2e[wave];

    float pt = 0.f, sg = 1.f, q = 0.f;
    if (d < n) {
        if (lane < 33) {
            pt = (dim == 0) ? tail[(size_t)d*3 + 1]
               : (dim == 1) ? tail[(size_t)d*3 + 2]
               : time_[d];
            sg = sigma[(size_t)d*3 + dim];
        }
        q = charge[d];
    }

    for (int it = 0; it < niter; ++it) {
        const bool active = (d < n);
        const int dn = d + nwaves;

        // ---- phase A: 33 edge CDFs in lanes 0..32 ----
        float cdf = 0.0f, iminf = 0.0f;
        if (lane < 33) {
            iminf = floorf((pt - 3.0f * sg) / gdim);
            float edge = (iminf + (float)k) * gdim;
            float z = (edge - pt) / (sg * 1.4142135623730951f);
            cdf = 0.5f * (1.0f + erff(z));
        }
        float cdf1 = __shfl_down(cdf, 1);
        float wv = cdf1 - cdf;            // per-cell weight, valid where k<10

        if (active && lane < 33 && k == 0)
            out_off[(size_t)d*3 + dim] = iminf;

        // ---- prefetch next depo's inputs (overlaps with A2+B) ----
        float npt = 0.f, nsg = 1.f, nq = 0.f;
        if (dn < n) {
            if (lane < 33) {
                npt = (dim == 0) ? tail[(size_t)dn*3 + 1]
                    : (dim == 1) ? tail[(size_t)dn*3 + 2]
                    : time_[dn];
                nsg = sigma[(size_t)dn*3 + dim];
            }
            nq = charge[dn];
        }

        // ---- phase A2: build qw01 table + w2 wrap table (wave-local) ----
        {
            float w0a = __shfl(wv, s0a);
            float w1a = __shfl(wv, s1a);
            s_qw01[wave][i0a] = q * w0a * w1a;
            float w0b = __shfl(wv, s0b);
            float w1b = __shfl(wv, s1b);
            if (i0b < 100) s_qw01[wave][i0b] = q * w0b * w1b;
            if (lane >= 22 && lane < 32) s_w2e[wave][lane - 22] = wv;
            if (lane >= 22 && lane < 25) s_w2e[wave][lane - 22 + 10] = wv;
        }
        // same-wave DS ops are in-order; no __syncthreads needed (per-wave data)

        // ---- phase B: 250 f32x4 stores, 2 merged DS reads per chunk ----
        if (active) {
            float* base = out_r + (size_t)d * 1000;
            #pragma unroll
            for (int cc = 0; cc < 4; ++cc) {
                if (on[cc]) {
                    float a = qw[jc[cc]];
                    float b = qw[jc[cc] + 1];          // only used when cross
                    f32x2 wlo = *reinterpret_cast<const f32x2*>(&w2e[i2c[cc]]);
                    f32x2 whi = *reinterpret_cast<const f32x2*>(&w2e[i2c[cc] + 2]);
                    float qzw = cross[cc] ? b : a;
                    f32x4 v;
                    v.x = a   * wlo.x;
                    v.y = a   * wlo.y;
                    v.z = qzw * whi.x;
                    v.w = qzw * whi.y;
                    *reinterpret_cast<f32x4*>(base + 4 * (lane + 64 * cc)) = v;
                }
            }
        }

        d = dn; pt = npt; sg = nsg; q = nq;
    }
}

extern "C" void kernel_launch(void* const* d_in, const int* in_sizes, int n_in,
                              void* d_out, int out_size, void* d_ws, size_t ws_size,
                              hipStream_t stream) {
    const float* sigma  = (const float*)d_in[0];
    const float* time_  = (const float*)d_in[1];
    const float* charge = (const float*)d_in[2];
    const float* tail   = (const float*)d_in[3];
    const float* gsp    = (const float*)d_in[4];

    const int n = in_sizes[1];          // N depos (time is [N])
    float* out_r   = (float*)d_out;
    float* out_off = out_r + (size_t)n * 1000;

    const int blocks = 4096;            // best-performing config (R3)
    const int nwaves = blocks * WAVES_PER_BLOCK;
    const int niter  = (n + nwaves - 1) / nwaves;

    raster_kernel<<<blocks, BLOCK, 0, stream>>>(sigma, time_, charge, tail, gsp,
                                                out_r, out_off, n, niter);
}